// Round 1
// baseline (431.471 us; speedup 1.0000x reference)
//
#include <hip/hip_runtime.h>

typedef __attribute__((ext_vector_type(8))) short short8;
typedef __attribute__((ext_vector_type(4))) float f32x4;
typedef unsigned short u16;
typedef unsigned int u32;

#define NH 16

__device__ __forceinline__ u16 f2bf(float f) {
  union { float f; u32 u; } v; v.f = f;
  u32 r = (v.u + 0x7fffu + ((v.u >> 16) & 1u)) >> 16;
  return (u16)r;
}

// ---------- convert x + Wq,Wk,Wv,Wo (fp32) -> bf16 into ws ----------
// layout (u16 elems): [x 8388608][Wq 1048576][Wk][Wv][Wo]
__global__ __launch_bounds__(256) void k_convert(
    const float* __restrict__ x, const float* __restrict__ wq,
    const float* __restrict__ wk, const float* __restrict__ wv,
    const float* __restrict__ wo, u16* __restrict__ dst) {
  int i = blockIdx.x * 256 + threadIdx.x;  // float4 chunk index
  size_t e = (size_t)i * 4;
  const float* s; size_t off;
  if (e < 8388608ull)       { s = x;  off = e; }
  else if (e < 9437184ull)  { s = wq; off = e - 8388608ull; }
  else if (e < 10485760ull) { s = wk; off = e - 9437184ull; }
  else if (e < 11534336ull) { s = wv; off = e - 10485760ull; }
  else                      { s = wo; off = e - 11534336ull; }
  float4 d = *(const float4*)(s + off);
  ushort4 o;
  o.x = f2bf(d.x); o.y = f2bf(d.y); o.z = f2bf(d.z); o.w = f2bf(d.w);
  *(ushort4*)(dst + e) = o;
}

// ---------- shared GEMM core: C[128x128] = A[128xK] * B[128xK]^T ----------
// A row-major [M][1024] bf16, B row-major [N][1024] bf16, both k-contiguous.
// LDS stride 72 u16 (=144B): keeps b128 16B-aligned, breaks bank aliasing.
#define GEMM_CORE(Aptr, Bptr)                                                   \
  __shared__ u16 As[128 * 72];                                                  \
  __shared__ u16 Bs[128 * 72];                                                  \
  const int tid = threadIdx.x;                                                  \
  const int wave = tid >> 6, lane = tid & 63;                                   \
  const int wr = wave >> 1, wc = wave & 1;                                      \
  const int quad = lane >> 4, l16 = lane & 15;                                  \
  const int m0 = blockIdx.y * 128, n0 = blockIdx.x * 128;                       \
  f32x4 acc[4][4];                                                              \
  {                                                                             \
    f32x4 z = {0.f, 0.f, 0.f, 0.f};                                             \
    for (int a = 0; a < 4; ++a) for (int b2 = 0; b2 < 4; ++b2) acc[a][b2] = z;  \
  }                                                                             \
  for (int k0 = 0; k0 < 1024; k0 += 64) {                                       \
    _Pragma("unroll")                                                           \
    for (int i = 0; i < 4; ++i) {                                               \
      int c = i * 256 + tid;                                                    \
      int row = c >> 3, cc = c & 7;                                             \
      *(uint4*)(&As[row * 72 + cc * 8]) =                                       \
          *(const uint4*)(Aptr + (size_t)(m0 + row) * 1024 + k0 + cc * 8);      \
      *(uint4*)(&Bs[row * 72 + cc * 8]) =                                       \
          *(const uint4*)(Bptr + (size_t)(n0 + row) * 1024 + k0 + cc * 8);      \
    }                                                                           \
    __syncthreads();                                                            \
    _Pragma("unroll")                                                           \
    for (int ks = 0; ks < 2; ++ks) {                                            \
      short8 af[4], bfr[4];                                                     \
      _Pragma("unroll")                                                         \
      for (int t = 0; t < 4; ++t)                                               \
        af[t] = *(const short8*)(&As[(wr * 64 + t * 16 + l16) * 72 + ks * 32 + quad * 8]); \
      _Pragma("unroll")                                                         \
      for (int t = 0; t < 4; ++t)                                               \
        bfr[t] = *(const short8*)(&Bs[(wc * 64 + t * 16 + l16) * 72 + ks * 32 + quad * 8]); \
      _Pragma("unroll")                                                         \
      for (int mt = 0; mt < 4; ++mt) {                                          \
        _Pragma("unroll")                                                       \
        for (int nt = 0; nt < 4; ++nt)                                          \
          acc[mt][nt] = __builtin_amdgcn_mfma_f32_16x16x32_bf16(                \
              af[mt], bfr[nt], acc[mt][nt], 0, 0, 0);                           \
      }                                                                         \
    }                                                                           \
    __syncthreads();                                                            \
  }

// ---------- QKV projection: out scattered to [B,H,T,Dh] bf16 ----------
__global__ __launch_bounds__(256, 2) void k_gemm_qkv(
    const u16* __restrict__ A, const u16* __restrict__ W,
    const float* __restrict__ bq, const float* __restrict__ bk,
    const float* __restrict__ bv, u16* __restrict__ qkv) {
  const int z = blockIdx.z;
  const u16* Bw = W + (size_t)z * 1048576;
  const float* bias = (z == 0) ? bq : (z == 1) ? bk : bv;
  u16* out = qkv + (size_t)z * 8388608;
  GEMM_CORE(A, Bw)
  const float scl = (z == 0) ? 0.125f : 1.0f;  // fold 1/sqrt(64) into q
  #pragma unroll
  for (int mt = 0; mt < 4; ++mt) {
    #pragma unroll
    for (int nt = 0; nt < 4; ++nt) {
      int n = n0 + wc * 64 + nt * 16 + l16;
      float bn = bias[n];
      int h = n >> 6, d = n & 63;
      #pragma unroll
      for (int r = 0; r < 4; ++r) {
        int m = m0 + wr * 64 + mt * 16 + quad * 4 + r;
        int b = m >> 11, t = m & 2047;
        float val = (acc[mt][nt][r] + bn) * scl;
        out[(((size_t)(b * NH + h) * 2048 + t) << 6) + d] = f2bf(val);
      }
    }
  }
}

// ---------- output projection: fp32 out [8192][1024] ----------
__global__ __launch_bounds__(256, 2) void k_gemm_out(
    const u16* __restrict__ A, const u16* __restrict__ Bw,
    const float* __restrict__ bias, float* __restrict__ out) {
  GEMM_CORE(A, Bw)
  #pragma unroll
  for (int mt = 0; mt < 4; ++mt) {
    #pragma unroll
    for (int nt = 0; nt < 4; ++nt) {
      int n = n0 + wc * 64 + nt * 16 + l16;
      float bn = bias[n];
      #pragma unroll
      for (int r = 0; r < 4; ++r) {
        int m = m0 + wr * 64 + mt * 16 + quad * 4 + r;
        out[(size_t)m * 1024 + n] = acc[mt][nt][r] + bn;
      }
    }
  }
}

// ---------- V transpose: [B,H,T,Dh] -> [B,H,Dh,T] bf16 ----------
__global__ __launch_bounds__(256) void k_vtrans(const u16* __restrict__ v,
                                                u16* __restrict__ vt) {
  int t0 = blockIdx.x * 64;
  int bh = blockIdx.y;
  const u16* vs = v + (size_t)bh * 2048 * 64;
  u16* vd = vt + (size_t)bh * 64 * 2048;
  int tid = threadIdx.x;
  #pragma unroll
  for (int it = 0; it < 2; ++it) {
    int c = it * 256 + tid;
    int d = c >> 3, tc = c & 7;
    union { u16 s[8]; uint4 q; } tmp;
    #pragma unroll
    for (int j = 0; j < 8; ++j)
      tmp.s[j] = vs[(size_t)(t0 + tc * 8 + j) * 64 + d];
    *(uint4*)(vd + (size_t)d * 2048 + t0 + tc * 8) = tmp.q;
  }
}

// ---------- flash attention: per (bh, 64-row q tile) ----------
__global__ __launch_bounds__(256, 2) void k_attn(
    const u16* __restrict__ q, const u16* __restrict__ k,
    const u16* __restrict__ vt, u16* __restrict__ y) {
  const int tid = threadIdx.x;
  const int wave = tid >> 6, lane = tid & 63;
  const int quad = lane >> 4, l16 = lane & 15;
  const int qt = blockIdx.x, bh = blockIdx.y;
  const int b = bh >> 4, h = bh & 15;

  __shared__ u16 Ks[64 * 72];
  __shared__ u16 Vs[64 * 72];   // [d][kidx] from v_t
  __shared__ u16 Ps[4 * 16 * 72];

  // Q fragments live in registers the whole kernel (reused every k-tile).
  const u16* qb = q + ((size_t)bh * 2048 + qt * 64 + wave * 16 + l16) * 64;
  short8 qf0 = *(const short8*)(qb + quad * 8);
  short8 qf1 = *(const short8*)(qb + 32 + quad * 8);

  f32x4 o[4];
  { f32x4 z = {0.f,0.f,0.f,0.f}; for (int dt = 0; dt < 4; ++dt) o[dt] = z; }
  float m_i[4] = {-1e30f, -1e30f, -1e30f, -1e30f};
  float l_i[4] = {0.f, 0.f, 0.f, 0.f};

  for (int kt = 0; kt <= qt; ++kt) {
    const u16* kb = k + ((size_t)bh * 2048 + kt * 64) * 64;
    const u16* vb = vt + (size_t)bh * 64 * 2048 + kt * 64;
    #pragma unroll
    for (int i = 0; i < 2; ++i) {
      int c = i * 256 + tid;
      int row = c >> 3, cc = c & 7;
      *(uint4*)(&Ks[row * 72 + cc * 8]) = *(const uint4*)(kb + (size_t)row * 64 + cc * 8);
      *(uint4*)(&Vs[row * 72 + cc * 8]) = *(const uint4*)(vb + (size_t)row * 2048 + cc * 8);
    }
    __syncthreads();

    // S = Q K^T  (q pre-scaled by 0.125)
    f32x4 s[4];
    #pragma unroll
    for (int nt = 0; nt < 4; ++nt) {
      short8 kf0 = *(const short8*)(&Ks[(nt * 16 + l16) * 72 + quad * 8]);
      short8 kf1 = *(const short8*)(&Ks[(nt * 16 + l16) * 72 + 32 + quad * 8]);
      f32x4 z4 = {0.f, 0.f, 0.f, 0.f};
      z4 = __builtin_amdgcn_mfma_f32_16x16x32_bf16(qf0, kf0, z4, 0, 0, 0);
      s[nt] = __builtin_amdgcn_mfma_f32_16x16x32_bf16(qf1, kf1, z4, 0, 0, 0);
    }

    if (kt == qt) {  // diagonal tile: causal mask (tiles kt<qt are fully valid)
      #pragma unroll
      for (int nt = 0; nt < 4; ++nt) {
        int kg = nt * 16 + l16;
        #pragma unroll
        for (int r = 0; r < 4; ++r) {
          int qg = wave * 16 + quad * 4 + r;
          if (kg > qg) s[nt][r] = -1e30f;
        }
      }
    }

    // online softmax per local row (row r held across the 16 lanes of a quad)
    u16* pw = Ps + wave * 16 * 72;
    #pragma unroll
    for (int r = 0; r < 4; ++r) {
      float mx = fmaxf(fmaxf(s[0][r], s[1][r]), fmaxf(s[2][r], s[3][r]));
      #pragma unroll
      for (int off = 8; off >= 1; off >>= 1)
        mx = fmaxf(mx, __shfl_xor(mx, off, 64));
      float mnew = fmaxf(m_i[r], mx);
      float alpha = __expf(m_i[r] - mnew);
      m_i[r] = mnew;
      float sum = 0.f;
      #pragma unroll
      for (int nt = 0; nt < 4; ++nt) {
        float p = __expf(s[nt][r] - mnew);
        sum += p;
        pw[(quad * 4 + r) * 72 + nt * 16 + l16] = f2bf(p);  // C-layout -> LDS
      }
      #pragma unroll
      for (int off = 8; off >= 1; off >>= 1)
        sum += __shfl_xor(sum, off, 64);
      l_i[r] = l_i[r] * alpha + sum;
      #pragma unroll
      for (int dt = 0; dt < 4; ++dt) o[dt][r] *= alpha;
    }

    // O += P * V   (P re-read from LDS in A-operand layout)
    #pragma unroll
    for (int ks = 0; ks < 2; ++ks) {
      short8 pf = *(const short8*)(pw + l16 * 72 + ks * 32 + quad * 8);
      #pragma unroll
      for (int dt = 0; dt < 4; ++dt) {
        short8 vf = *(const short8*)(&Vs[(dt * 16 + l16) * 72 + ks * 32 + quad * 8]);
        o[dt] = __builtin_amdgcn_mfma_f32_16x16x32_bf16(pf, vf, o[dt], 0, 0, 0);
      }
    }
    __syncthreads();
  }

  // epilogue: y[b][t][h][d] = O / l
  #pragma unroll
  for (int dt = 0; dt < 4; ++dt) {
    #pragma unroll
    for (int r = 0; r < 4; ++r) {
      int t = qt * 64 + wave * 16 + quad * 4 + r;
      int d = dt * 16 + l16;
      float val = o[dt][r] / l_i[r];
      y[(((size_t)b * 2048 + t) * NH + h) * 64 + d] = f2bf(val);
    }
  }
}

extern "C" void kernel_launch(void* const* d_in, const int* in_sizes, int n_in,
                              void* d_out, int out_size, void* d_ws, size_t ws_size,
                              hipStream_t stream) {
  const float* x  = (const float*)d_in[0];
  const float* Wq = (const float*)d_in[1];
  const float* bq = (const float*)d_in[2];
  const float* Wk = (const float*)d_in[3];
  const float* bk = (const float*)d_in[4];
  const float* Wv = (const float*)d_in[5];
  const float* bv = (const float*)d_in[6];
  const float* Wo = (const float*)d_in[7];
  const float* bo = (const float*)d_in[8];
  float* out = (float*)d_out;

  u16* ws  = (u16*)d_ws;
  u16* xb  = ws;                   // 8388608   x bf16 [8192][1024]
  u16* Wb  = ws + 8388608;         // 4x1048576 Wq|Wk|Wv|Wo bf16
  u16* qkv = ws + 12582912;        // 3x8388608 q|k|v [B,H,T,Dh] bf16
  u16* vt  = ws + 37748736;        // 8388608   v^T [B,H,Dh,T] bf16
  u16* y   = ws + 46137344;        // 8388608   attn out [B,T,H,Dh] bf16
  // total 54525952 u16 = 104 MB of d_ws

  k_convert<<<dim3(12288), dim3(256), 0, stream>>>(x, Wq, Wk, Wv, Wo, ws);
  k_gemm_qkv<<<dim3(8, 64, 3), dim3(256), 0, stream>>>(xb, Wb, bq, bk, bv, qkv);
  k_vtrans<<<dim3(32, 64), dim3(256), 0, stream>>>(qkv + 2 * 8388608, vt);
  k_attn<<<dim3(32, 64), dim3(256), 0, stream>>>(qkv, qkv + 8388608, vt, y);
  k_gemm_out<<<dim3(8, 64), dim3(256), 0, stream>>>(y, Wb + 3 * 1048576, bo, out);
}